// Round 17
// baseline (378.462 us; speedup 1.0000x reference)
//
#include <hip/hip_runtime.h>
#include <hip/hip_bf16.h>
#include <stdint.h>

// ---------------------------------------------------------------------------
// TransformerBlock: rms1 -> QKV(+RoPE) -> window-512 flash attn -> out-proj(+x)
//                   -> rms2(+gate logits) -> top2 route -> grouped SwiGLU MoE -> +x2
// Round 17: w2-conv load split into quarters across QKV / attn / proj / ffn1
// windows (r16 had all 8192 tiles in the ffn1 window -> 139us critical
// dispatch). Tile partition: QKV t[0,2048), attn t[2048,4096),
// proj t[4096,6144), ffn1 t[6144,8192). All deps safe (w2T first read @ffn2).
// ---------------------------------------------------------------------------

#define S_ 2048
#define HID_ 1024
#define NH_ 16
#define HD_ 64
#define WIN_ 512
#define DFF_ 4096
#define NE_ 8

typedef unsigned short u16;
typedef __attribute__((ext_vector_type(8))) short short8;
typedef __attribute__((ext_vector_type(4))) float f32x4;

__device__ __forceinline__ u16 f2bf(float f) {
  union { float f; unsigned u; } v; v.f = f;
  unsigned r = (v.u + 0x7FFFu + ((v.u >> 16) & 1u)) >> 16;
  return (u16)r;
}
__device__ __forceinline__ float bf2f(u16 b) {
  union { unsigned u; float f; } v; v.u = ((unsigned)b) << 16;
  return v.f;
}

// async global->LDS, 16B per lane. LDS dest wave-uniform base + lane*16.
__device__ __forceinline__ void gload16(const void* g, void* l) {
  __builtin_amdgcn_global_load_lds(
      (const __attribute__((address_space(1))) void*)g,
      (__attribute__((address_space(3))) void*)l, 16, 0, 0);
}

template <int N>
__device__ __forceinline__ void waitcnt_vm() {
  static_assert(N == 0 || N == 2 || N == 4 || N == 6 || N == 8 || N == 12 ||
                N == 16 || N == 24, "unsupported vmcnt");
  if constexpr (N == 0) asm volatile("s_waitcnt vmcnt(0)" ::: "memory");
  else if constexpr (N == 2) asm volatile("s_waitcnt vmcnt(2)" ::: "memory");
  else if constexpr (N == 4) asm volatile("s_waitcnt vmcnt(4)" ::: "memory");
  else if constexpr (N == 6) asm volatile("s_waitcnt vmcnt(6)" ::: "memory");
  else if constexpr (N == 8) asm volatile("s_waitcnt vmcnt(8)" ::: "memory");
  else if constexpr (N == 12) asm volatile("s_waitcnt vmcnt(12)" ::: "memory");
  else if constexpr (N == 16) asm volatile("s_waitcnt vmcnt(16)" ::: "memory");
  else if constexpr (N == 24) asm volatile("s_waitcnt vmcnt(24)" ::: "memory");
}

// ------------- 64x64 f32->bf16 transpose tile (r10 proven, 256 thr) ---------
// LDS: element (k,n) at byte k*264 + ((n>>2)^((k>>2)&15))*8 + (n&3)*2.
// Needs 64*264 = 16896 bytes of T.
__device__ __forceinline__ void conv64(const float* __restrict__ Wm,
                                       u16* __restrict__ WTm, int K, int N,
                                       int n0, int k0, char* T, int tid) {
  int m = tid & 15, rr = tid >> 4;
#pragma unroll
  for (int p = 0; p < 4; ++p) {
    int k = p * 16 + rr;
    float4 v = *(const float4*)&Wm[(size_t)(k0 + k) * N + n0 + m * 4];
    uint2 pk;
    pk.x = (unsigned)f2bf(v.x) | ((unsigned)f2bf(v.y) << 16);
    pk.y = (unsigned)f2bf(v.z) | ((unsigned)f2bf(v.w) << 16);
    *(uint2*)(T + k * 264 + ((m ^ ((k >> 2) & 15)) << 3)) = pk;
  }
  __syncthreads();
#pragma unroll
  for (int p = 0; p < 4; ++p) {
    int n = p * 16 + rr;
    int un = n >> 2, lo2 = (n & 3) * 2;
    ushort4 o;
#pragma unroll
    for (int j = 0; j < 4; ++j) {
      int k = m * 4 + j;
      ((u16*)&o)[j] =
          *(const u16*)(T + k * 264 + ((un ^ ((k >> 2) & 15)) << 3) + lo2);
    }
    *(ushort4*)&WTm[(size_t)(n0 + n) * K + k0 + m * 4] = o;
  }
}

// bf16 [K][N] -> bf16 [N][K] (for V: [s][d] -> [d][s] per head)
__global__ __launch_bounds__(256) void convT_u16_k(const u16* __restrict__ W,
                                                   u16* __restrict__ WT,
                                                   int K, int N, size_t matStride) {
  __shared__ u16 t[64][66];
  const u16* Wm = W + (size_t)blockIdx.z * matStride;
  u16* WTm = WT + (size_t)blockIdx.z * matStride;
  int n0 = blockIdx.x * 64, k0 = blockIdx.y * 64;
  int tid = threadIdx.x;
  int c2 = (tid & 31) * 2, rr = tid >> 5;
#pragma unroll
  for (int it = 0; it < 8; ++it) {
    int r = it * 8 + rr;
    unsigned vv = *(const unsigned*)&Wm[(size_t)(k0 + r) * N + n0 + c2];
    t[c2][r] = (u16)vv;
    t[c2 + 1][r] = (u16)(vv >> 16);
  }
  __syncthreads();
#pragma unroll
  for (int it = 0; it < 8; ++it) {
    int n = it * 8 + rr;
    unsigned pk = (unsigned)t[n][c2] | ((unsigned)t[n][c2 + 1] << 16);
    *(unsigned*)&WTm[(size_t)(n0 + n) * K + k0 + c2] = pk;
  }
}

// ------------- mega1: rms1 (0..2047) + rope (2048..2303) + qkvo conv --------
__global__ __launch_bounds__(256) void mega1_k(
    const float* __restrict__ x, const float* __restrict__ rw,
    u16* __restrict__ y, const float* __restrict__ rot,
    float* __restrict__ cost, float* __restrict__ sint,
    const float* __restrict__ wq, const float* __restrict__ wk,
    const float* __restrict__ wv, const float* __restrict__ wo,
    u16* __restrict__ qkvoT) {
  __shared__ alignas(16) char SM[16896];
  int b = blockIdx.x, tid = threadIdx.x;
  if (b >= S_ + 256) {
    int cb = b - (S_ + 256);
    int z = cb >> 8, rem = cb & 255;
    const float* Wm = (z == 0) ? wq : (z == 1) ? wk : (z == 2) ? wv : wo;
    u16* WTm = qkvoT + (size_t)z * HID_ * HID_;
    conv64(Wm, WTm, HID_, HID_, (rem & 15) * 64, (rem >> 4) * 64, SM, tid);
    return;
  }
  if (b >= S_) {
    int id = (b - S_) * 256 + tid;
    int s = id >> 5, j = id & 31;
    cost[id] = rot[(size_t)s * 4096 + (size_t)(2 * j) * 64 + 2 * j];
    sint[id] = rot[(size_t)s * 4096 + (size_t)(2 * j + 1) * 64 + 2 * j];
    return;
  }
  int row = b;
  float* red = (float*)SM;
  const float4 v = *(const float4*)&x[(size_t)row * HID_ + tid * 4];
  float ss = v.x * v.x + v.y * v.y + v.z * v.z + v.w * v.w;
#pragma unroll
  for (int o = 32; o; o >>= 1) ss += __shfl_xor(ss, o);
  if ((tid & 63) == 0) red[tid >> 6] = ss;
  __syncthreads();
  float rstd = rsqrtf((red[0] + red[1] + red[2] + red[3]) * (1.f / HID_) + 1e-6f);
  const float4 w4 = *(const float4*)&rw[tid * 4];
  ushort4 o4;
  o4.x = f2bf(v.x * rstd * w4.x);
  o4.y = f2bf(v.y * rstd * w4.y);
  o4.z = f2bf(v.z * rstd * w4.z);
  o4.w = f2bf(v.w * rstd * w4.w);
  *(ushort4*)&y[(size_t)row * HID_ + tid * 4] = o4;
}

// ------------------------- rmsnorm 2 + gate logits --------------------------
__global__ __launch_bounds__(256) void rms2_gate_k(const float* __restrict__ x2,
                                                   const float* __restrict__ rw,
                                                   const float* __restrict__ gw,
                                                   u16* __restrict__ y2,
                                                   float* __restrict__ logits) {
  int row = blockIdx.x, tid = threadIdx.x;
  int wv = tid >> 6, ln = tid & 63;
  const float4 v = *(const float4*)&x2[(size_t)row * HID_ + tid * 4];
  float ss = v.x * v.x + v.y * v.y + v.z * v.z + v.w * v.w;
#pragma unroll
  for (int o = 32; o; o >>= 1) ss += __shfl_xor(ss, o);
  __shared__ float red[4];
  __shared__ float lred[4][8];
  if (ln == 0) red[wv] = ss;
  __syncthreads();
  float rstd = rsqrtf((red[0] + red[1] + red[2] + red[3]) * (1.f / HID_) + 1e-6f);
  const float4 w4 = *(const float4*)&rw[tid * 4];
  float yv[4];
  yv[0] = v.x * rstd * w4.x; yv[1] = v.y * rstd * w4.y;
  yv[2] = v.z * rstd * w4.z; yv[3] = v.w * rstd * w4.w;
  ushort4 o4;
  o4.x = f2bf(yv[0]); o4.y = f2bf(yv[1]); o4.z = f2bf(yv[2]); o4.w = f2bf(yv[3]);
  *(ushort4*)&y2[(size_t)row * HID_ + tid * 4] = o4;
  float le[8] = {0, 0, 0, 0, 0, 0, 0, 0};
  int d0 = tid * 4;
#pragma unroll
  for (int j = 0; j < 4; ++j) {
    const float* grow = &gw[(size_t)(d0 + j) * NE_];
#pragma unroll
    for (int e = 0; e < 8; ++e) le[e] += yv[j] * grow[e];
  }
#pragma unroll
  for (int e = 0; e < 8; ++e) {
    float t = le[e];
#pragma unroll
    for (int o = 32; o; o >>= 1) t += __shfl_xor(t, o);
    le[e] = t;
  }
  if (ln == 0)
#pragma unroll
    for (int e = 0; e < 8; ++e) lred[wv][e] = le[e];
  __syncthreads();
  if (tid < 8)
    logits[(size_t)row * NE_ + tid] =
        lred[0][tid] + lred[1][tid] + lred[2][tid] + lred[3][tid];
}

// ---------------------- routing: top2 + prefix + scatter --------------------
__global__ __launch_bounds__(1024) void route_k(const float* __restrict__ logits,
                                                int* __restrict__ topi,
                                                float* __restrict__ topg,
                                                int* __restrict__ counts,
                                                int* __restrict__ ebase,
                                                int* __restrict__ slot_token,
                                                int* __restrict__ slot_of) {
  __shared__ int cnt[8], bas[8], rnk[8];
  int tid = threadIdx.x;
  if (tid < 8) { cnt[tid] = 0; rnk[tid] = 0; }
  __syncthreads();
  int e0[2], e1[2];
  float g0[2], g1[2];
#pragma unroll
  for (int s = 0; s < 2; ++s) {
    int t = tid * 2 + s;
    const float* lg = &logits[(size_t)t * NE_];
    float v0 = -1e30f; int i0 = 0;
#pragma unroll
    for (int e = 0; e < 8; ++e) {
      float x = lg[e];
      if (x > v0) { v0 = x; i0 = e; }
    }
    float v1 = -1e30f; int i1 = 0;
#pragma unroll
    for (int e = 0; e < 8; ++e) {
      if (e == i0) continue;
      float x = lg[e];
      if (x > v1) { v1 = x; i1 = e; }
    }
    float ex = __expf(v1 - v0);
    e0[s] = i0; e1[s] = i1;
    g0[s] = 1.f / (1.f + ex);
    g1[s] = ex / (1.f + ex);
    topi[t * 2] = i0; topi[t * 2 + 1] = i1;
    topg[t * 2] = g0[s]; topg[t * 2 + 1] = g1[s];
    atomicAdd(&cnt[i0], 1);
    atomicAdd(&cnt[i1], 1);
  }
  __syncthreads();
  if (tid == 0) {
    int s = 0;
    for (int e = 0; e < 8; ++e) { bas[e] = s; s += cnt[e]; }
  }
  __syncthreads();
#pragma unroll
  for (int s = 0; s < 2; ++s) {
    int t = tid * 2 + s;
    int p0 = bas[e0[s]] + atomicAdd(&rnk[e0[s]], 1);
    int p1 = bas[e1[s]] + atomicAdd(&rnk[e1[s]], 1);
    slot_token[p0] = t; slot_token[p1] = t;
    slot_of[t * 2] = p0; slot_of[t * 2 + 1] = p1;
  }
  if (tid < 8) { counts[tid] = cnt[tid]; ebase[tid] = bas[tid]; }
}

// ----------------- GEMM: 4-wave 128^2 BK=32, SLOTS-deep pipeline ------------
// MODE 0: qkv; z in [3,35) w3-conv (mats 0..3 -> w13T slots 8..11);
//              z in [35,51) w2-conv tiles t[0,2048)
// MODE 1: out-proj(+x); z in [1,33) w3-conv (mats 4..7 -> slots 12..15);
//              z in [33,49) w2-conv tiles t[4096,6144)
// MODE 4: ffn2 split-K f32-partial (no conv arm)
template <int MODE, int SLOTS>
__global__ __launch_bounds__(256, (SLOTS <= 3 ? 3 : (SLOTS <= 5 ? 2 : 1)))
void gemm3_k(
    const u16* __restrict__ A, const u16* __restrict__ B0,
    const u16* __restrict__ B1, const u16* __restrict__ B2, int K,
    const int* __restrict__ ecnt, const int* __restrict__ ebase,
    const float* __restrict__ cost, const float* __restrict__ sint,
    const float* __restrict__ xres, float* __restrict__ outf,
    u16* __restrict__ o0, u16* __restrict__ o1, u16* __restrict__ o2,
    const float* __restrict__ c2src, u16* __restrict__ c2dst) {
  constexpr int WVM = 4 * (SLOTS - 2);
  __shared__ alignas(16) char smem[SLOTS * 16384];

  if constexpr (MODE == 0) {
    if (blockIdx.z >= 35) {  // w2-conv arm: tiles t in [0,2048)
      int t = (blockIdx.z - 35) * 128 + blockIdx.y * 8 + blockIdx.x;
      int mt = t >> 10, rem = t & 1023;
      conv64(c2src + (size_t)mt * DFF_ * HID_,
             c2dst + (size_t)mt * DFF_ * HID_, DFF_, HID_,
             (rem & 15) * 64, (rem >> 4) * 64, smem, threadIdx.x);
      return;
    }
    if (blockIdx.z >= 3) {  // w3-conv arm: lower-half mats -> w13T slots 8..11
      int idx = (blockIdx.z - 3) * 128 + blockIdx.y * 8 + blockIdx.x;
      int mt = idx >> 10, rem = idx & 1023;
      conv64(xres + (size_t)mt * HID_ * DFF_,
             (u16*)outf + (size_t)(8 + mt) * HID_ * DFF_, HID_, DFF_,
             (rem & 63) * 64, (rem >> 6) * 64, smem, threadIdx.x);
      return;
    }
  }
  if constexpr (MODE == 1) {
    if (blockIdx.z >= 33) {  // w2-conv arm: tiles t in [4096,6144)
      int t = 4096 + (blockIdx.z - 33) * 128 + blockIdx.y * 8 + blockIdx.x;
      int mt = t >> 10, rem = t & 1023;
      conv64(c2src + (size_t)mt * DFF_ * HID_,
             c2dst + (size_t)mt * DFF_ * HID_, DFF_, HID_,
             (rem & 15) * 64, (rem >> 4) * 64, smem, threadIdx.x);
      return;
    }
    if (blockIdx.z >= 1) {  // w3-conv arm: upper-half mats -> w13T slots 12..15
      int idx = (blockIdx.z - 1) * 128 + blockIdx.y * 8 + blockIdx.x;
      int mt = idx >> 10, rem = idx & 1023;
      conv64(cost + (size_t)(4 + mt) * HID_ * DFF_,
             o1 + (size_t)(12 + mt) * HID_ * DFF_, HID_, DFF_,
             (rem & 63) * 64, (rem >> 6) * 64, smem, threadIdx.x);
      return;
    }
  }

  int n0 = blockIdx.x * 128, m0 = blockIdx.y * 128;
  int cnt = 0, base = 0, kc = 0;
  const u16* Bp;
  u16* outb = o0;
  float* pout = outf;
  int rope = 0;
  if constexpr (MODE == 0) {
    int z = blockIdx.z;
    Bp = (z == 0) ? B0 : (z == 1) ? B1 : B2;
    outb = (z == 0) ? o0 : (z == 1) ? o1 : o2;
    rope = (z < 2) ? 1 : 0;
  } else if constexpr (MODE == 1) {
    Bp = B0;
  } else if constexpr (MODE == 4) {
    int e = blockIdx.z >> 1;
    kc = blockIdx.z & 1;
    cnt = ecnt[e]; base = ebase[e];
    if (m0 >= cnt) return;
    Bp = B0 + (size_t)e * HID_ * DFF_;
    pout = outf + (size_t)kc * ((size_t)2 * S_ * HID_);
  } else {
    int e = blockIdx.z;
    cnt = ecnt[e]; base = ebase[e];
    if (m0 >= cnt) return;
    Bp = B0 + (size_t)e * HID_ * DFF_;
  }

  int tid = threadIdx.x, w = tid >> 6, l = tid & 63, lo = l & 15, g = l >> 4;
  int wm = w >> 1, wn = w & 1;
  int KT = K >> 5;
  size_t rb = (MODE == 4) ? (size_t)DFF_ * 2 : (size_t)K * 2;
  size_t kcoff = (MODE == 4) ? (size_t)kc * (size_t)(DFF_ / 2) * 2 : 0;

  int lrow = l >> 2, lu = l & 3;
  const char* pA[2];
  const char* pB[2];
  int ldOff[2];
#pragma unroll
  for (int j = 0; j < 2; ++j) {
    int rA = j * 64 + w * 16 + lrow;
    int swz = (lu ^ ((rA >> 1) & 3)) << 4;
    size_t arow;
    if constexpr (MODE == 3 || MODE == 4) {
      arow = (size_t)(base + min(m0 + rA, cnt - 1));
    } else {
      arow = (size_t)(m0 + rA);
    }
    pA[j] = (const char*)A + arow * rb + kcoff + swz;
    pB[j] = (const char*)Bp + (size_t)(n0 + rA) * rb + kcoff + swz;
    ldOff[j] = (j * 64 + w * 16) * 64;
  }

  auto stage = [&](int t) {
    char* s = smem + (t % SLOTS) * 16384;
    size_t kb = (size_t)t * 64;
    gload16(pA[0] + kb, s + ldOff[0]);
    gload16(pA[1] + kb, s + ldOff[1]);
    gload16(pB[0] + kb, s + 8192 + ldOff[0]);
    gload16(pB[1] + kb, s + 8192 + ldOff[1]);
  };

  f32x4 acc[4][4];
#pragma unroll
  for (int i = 0; i < 4; ++i)
#pragma unroll
    for (int j = 0; j < 4; ++j) acc[i][j] = (f32x4){0.f, 0.f, 0.f, 0.f};

#pragma unroll
  for (int s = 0; s < SLOTS - 1; ++s) stage(min(s, KT - 1));
  waitcnt_vm<WVM>();
  __builtin_amdgcn_s_barrier();

  for (int t = 0; t < KT; ++t) {
    char* s = smem + (t % SLOTS) * 16384;
    stage(min(t + SLOTS - 1, KT - 1));
    short8 afr[4], bfr[4];
#pragma unroll
    for (int mi = 0; mi < 4; ++mi) {
      int r = wm * 64 + mi * 16 + lo;
      afr[mi] = *(const short8*)(s + r * 64 + ((g ^ ((r >> 1) & 3)) << 4));
    }
#pragma unroll
    for (int ni = 0; ni < 4; ++ni) {
      int r = wn * 64 + ni * 16 + lo;
      bfr[ni] = *(const short8*)(s + 8192 + r * 64 + ((g ^ ((r >> 1) & 3)) << 4));
    }
    asm volatile("s_waitcnt lgkmcnt(0)" ::: "memory");
    __builtin_amdgcn_s_setprio(1);
#pragma unroll
    for (int mi = 0; mi < 4; ++mi)
#pragma unroll
      for (int ni = 0; ni < 4; ++ni)
        acc[mi][ni] = __builtin_amdgcn_mfma_f32_16x16x32_bf16(afr[mi], bfr[ni], acc[mi][ni], 0, 0, 0);
    __builtin_amdgcn_s_setprio(0);
    if (t + 1 < KT)
      waitcnt_vm<WVM>();
    else
      waitcnt_vm<0>();
    __builtin_amdgcn_s_barrier();
  }
  asm volatile("s_waitcnt vmcnt(0) lgkmcnt(0)" ::: "memory");

  // epilogue
#pragma unroll
  for (int mi = 0; mi < 4; ++mi) {
    int lr = wm * 64 + mi * 16 + g * 4;
#pragma unroll
    for (int ni = 0; ni < 4; ++ni) {
      int c = n0 + wn * 64 + ni * 16 + lo;
#pragma unroll
      for (int r = 0; r < 4; ++r) {
        float v = acc[mi][ni][r];
        if constexpr (MODE == 0) {
          int row = m0 + lr + r;
          float p = __shfl_xor(v, 1);
          if (rope) {
            int dd = c & 63;
            float co = cost[(size_t)row * 32 + (dd >> 1)];
            float si = sint[(size_t)row * 32 + (dd >> 1)];
            v = (dd & 1) ? (co * v - si * p) : (co * v + si * p);
          }
          outb[((size_t)(c >> 6) * S_ + row) * HD_ + (c & 63)] = f2bf(v);
        } else if constexpr (MODE == 1) {
          int row = m0 + lr + r;
          outf[(size_t)row * HID_ + c] = v + xres[(size_t)row * HID_ + c];
        } else if constexpr (MODE == 4) {
          int m = m0 + lr + r;
          if (m < cnt) pout[(size_t)(base + m) * HID_ + c] = v;
        } else {
          int m = m0 + lr + r;
          if (m < cnt) outb[(size_t)(base + m) * HID_ + c] = f2bf(v);
        }
      }
    }
  }
}

// ----------------- GEMM: 8-wave 256^2 BK=64 (ffn1), 2-phase -----------------
// Flattened grid: blocks [0,1024) = ffn1; blocks [1024,2048) = w2-conv arm
// (2 tiles per 512-thr block, tiles t in [6144,8192)).
__global__ __launch_bounds__(512, 2) void gemm5_k(
    const u16* __restrict__ A, const u16* __restrict__ B0,
    const u16* __restrict__ B1, int K, const int* __restrict__ ecnt,
    const int* __restrict__ ebase, const int* __restrict__ slot_token,
    u16* __restrict__ o0, u16* __restrict__ o1,
    const float* __restrict__ w2f, u16* __restrict__ w2T) {
  constexpr int BM = 256;
  constexpr int MROW = 128;
  constexpr int MI = 8;
  constexpr int MH = 4;
  constexpr int ABYTES = BM * 128;
  __shared__ alignas(16) char smem[ABYTES * 4];  // 128 KB

  int bid = blockIdx.x;
  if (bid >= 1024) {  // w2-conv arm: two tiles per block, split LDS halves
    int t2 = bid - 1024;
    int tid = threadIdx.x;
    int half = tid >> 8;
    int t = 6144 + t2 * 2 + half;
    int mt = t >> 10, rem = t & 1023;
    conv64(w2f + (size_t)mt * DFF_ * HID_, w2T + (size_t)mt * DFF_ * HID_,
           DFF_, HID_, (rem & 15) * 64, (rem >> 4) * 64,
           smem + half * 16896, tid & 255);
    return;
  }

  char* ldsA = smem;
  char* ldsB = smem + 2 * ABYTES;
  int bx = bid & 15, by = (bid >> 4) & 3, bz = bid >> 6;
  int n0 = bx * BM, m0 = by * BM;
  int e = bz >> 1, mat = bz & 1;
  int cnt = ecnt[e], base = ebase[e];
  if (m0 >= cnt) return;
  const u16* Bp = (mat ? B1 : B0) + (size_t)e * DFF_ * HID_;
  u16* outb = mat ? o1 : o0;

  int tid = threadIdx.x, w = tid >> 6, l = tid & 63, lo = l & 15, g = l >> 4;
  int wm = w >> 2, wn = w & 3;
  int KT = K >> 6;
  size_t rb = (size_t)K * 2;

  int lrow = l >> 3, lu = l & 7;
  const char* pA[4];
  const char* pB[4];
  int ldOff[4];
#pragma unroll
  for (int j = 0; j < 4; ++j) {
    int rA = j * 64 + w * 8 + lrow;
    int swz = (lu ^ (rA & 7)) << 4;
    size_t arow = (size_t)slot_token[base + min(m0 + rA, cnt - 1)];
    pA[j] = (const char*)A + arow * rb + swz;
    pB[j] = (const char*)Bp + (size_t)(n0 + rA) * rb + swz;
    ldOff[j] = (j * 64 + w * 8) * 128;
  }

  auto stA = [&](int t, int j) {
    gload16(pA[j] + (size_t)t * 128, ldsA + (t & 1) * ABYTES + ldOff[j]);
  };
  auto stB = [&](int t, int j) {
    gload16(pB[j] + (size_t)t * 128, ldsB + (t & 1) * ABYTES + ldOff[j]);
  };
  auto rdA = [&](int d, int mi, int kh) {
    int row = wm * MROW + mi * 16 + lo;
    return *(const short8*)(ldsA + d * ABYTES + row * 128 +
                            (((kh * 4 + g) ^ (row & 7)) << 4));
  };
  auto rdB = [&](int d, int ni, int kh) {
    int row = wn * 64 + ni * 16 + lo;
    return *(const short8*)(ldsB + d * ABYTES + row * 128 +
                            (((kh * 4 + g) ^ (row & 7)) << 4));
  };

  f32x4 acc[MI][4];
#pragma unroll
  for (int i = 0; i < MI; ++i)
#pragma unroll
    for (int j = 0; j < 4; ++j) acc[i][j] = (f32x4){0.f, 0.f, 0.f, 0.f};

  // prologue: tile 0 in consumption order [B0-3, A0, A2, A1, A3]
  stB(0, 0); stB(0, 1); stB(0, 2); stB(0, 3);
  stA(0, 0); stA(0, 2); stA(0, 1); stA(0, 3);
  waitcnt_vm<2>();
  __builtin_amdgcn_s_barrier();

  for (int t = 0; t < KT; ++t) {
    int d = t & 1;
    int tn = min(t + 1, KT - 1);
    short8 afr[MH][2], bfr[4][2];
    // phase 0: q0 (A-even rows), both kh
    stB(tn, 0); stB(tn, 1); stB(tn, 2); stB(tn, 3);
#pragma unroll
    for (int i = 0; i < MH; ++i) {
      afr[i][0] = rdA(d, i, 0);
      afr[i][1] = rdA(d, i, 1);
    }
#pragma unroll
    for (int n = 0; n < 4; ++n) {
      bfr[n][0] = rdB(d, n, 0);
      bfr[n][1] = rdB(d, n, 1);
    }
    asm volatile("s_waitcnt lgkmcnt(0)" ::: "memory");
    __builtin_amdgcn_s_setprio(1);
#pragma unroll
    for (int kh = 0; kh < 2; ++kh)
#pragma unroll
      for (int i = 0; i < MH; ++i)
#pragma unroll
        for (int n = 0; n < 4; ++n)
          acc[i][n] = __builtin_amdgcn_mfma_f32_16x16x32_bf16(
              afr[i][kh], bfr[n][kh], acc[i][n], 0, 0, 0);
    __builtin_amdgcn_s_setprio(0);
    waitcnt_vm<4>();
    __builtin_amdgcn_s_barrier();
    // phase 1: q1 (A-odd rows), both kh
    stA(tn, 0); stA(tn, 2); stA(tn, 1); stA(tn, 3);
#pragma unroll
    for (int i = 0; i < MH; ++i) {
      afr[i][0] = rdA(d, MH + i, 0);
      afr[i][1] = rdA(d, MH + i, 1);
    }
    asm volatile("s_waitcnt lgkmcnt(0)" ::: "memory");
    __builtin_amdgcn_s_setprio(1);
#pragma unroll
    for (int kh = 0; kh < 2; ++kh)
#pragma unroll
      for (int i = 0; i < MH; ++i)
#pragma unroll
        for (int n = 0; n < 4; ++n)
          acc[MH + i][n] = __builtin_amdgcn_mfma_f32_16x16x32_bf16(
              afr[i][kh], bfr[n][kh], acc[MH + i][n], 0, 0, 0);
    __builtin_amdgcn_s_setprio(0);
    waitcnt_vm<2>();
    __builtin_amdgcn_s_barrier();
  }
  asm volatile("s_waitcnt vmcnt(0) lgkmcnt(0)" ::: "memory");

#pragma unroll
  for (int mi = 0; mi < MI; ++mi) {
    int lr = wm * MROW + mi * 16 + g * 4;
#pragma unroll
    for (int ni = 0; ni < 4; ++ni) {
      int c = n0 + wn * 64 + ni * 16 + lo;
#pragma unroll
      for (int r = 0; r < 4; ++r) {
        int m = m0 + lr + r;
        if (m < cnt) outb[(size_t)(base + m) * DFF_ + c] = f2bf(acc[mi][ni][r]);
      }
    }
  }
}

// ----------------------------- swiglu fuse ----------------------------------
__global__ __launch_bounds__(256) void swiglu_k(u16* __restrict__ h1,
                                                const u16* __restrict__ h3) {
  size_t i = ((size_t)blockIdx.x * 256 + threadIdx.x) * 8;
  short8 a = *(const short8*)(h1 + i);
  short8 b = *(const short8*)(h3 + i);
  short8 o;
#pragma unroll
  for (int j = 0; j < 8; ++j) {
    float x = bf2f((u16)a[j]), y = bf2f((u16)b[j]);
    float s = x / (1.f + __expf(-x));
    o[j] = (short)f2bf(s * y);
  }
  *(short8*)(h1 + i) = o;
}

// --- mega attn: attn (0..511) + w1-conv (512..8703) + w2-conv (8704..10751) -
__global__ __launch_bounds__(256) void attn_conv_k(
    const u16* __restrict__ qh, const u16* __restrict__ kh,
    const u16* __restrict__ vht, u16* __restrict__ attn,
    const float* __restrict__ w1, u16* __restrict__ w13T,
    const float* __restrict__ w2f, u16* __restrict__ w2T) {
  __shared__ alignas(16) char SM[24576];
  int bx = blockIdx.x, tid = threadIdx.x;
  if (bx >= 512 + 8192) {
    // w2-conv arm: tiles t in [2048,4096)
    int t = 2048 + (bx - 512 - 8192);
    int mt = t >> 10, rem = t & 1023;
    conv64(w2f + (size_t)mt * DFF_ * HID_, w2T + (size_t)mt * DFF_ * HID_,
           DFF_, HID_, (rem & 15) * 64, (rem >> 4) * 64, SM, tid);
    return;
  }
  if (bx >= 512) {
    // w1: K=1024, N=4096; 1024 tiles (64n x 16k) per z; z in [0,8)
    int cb = bx - 512;
    int z = cb >> 10, rem = cb & 1023;
    const float* Wm = w1 + (size_t)z * HID_ * DFF_;
    u16* WTm = w13T + (size_t)z * HID_ * DFF_;
    conv64(Wm, WTm, HID_, DFF_, (rem & 63) * 64, (rem >> 6) * 64, SM, tid);
    return;
  }
  // ----- attention arm -----
  int qt = bx & 31, h = bx >> 5;
  char* Ks = SM;
  char* Vs = SM + 8192;
  char* Ps = SM + 16384;
  int w = tid >> 6, l = tid & 63, lo = l & 15, g = l >> 4;
  char* Pw = Ps + w * 2048;
  int q0 = qt * 64, qw = q0 + w * 16;
  const u16* qhh = qh + ((size_t)h * S_ + qw) * HD_;
  short8 bq0 = *(const short8*)(qhh + lo * 64 + g * 8);
  short8 bq1 = *(const short8*)(qhh + lo * 64 + 32 + g * 8);
  int q = qw + lo;
  float m_run = -1e30f, l_run = 0.f;
  f32x4 o[4];
#pragma unroll
  for (int i = 0; i < 4; ++i) o[i] = (f32x4){0.f, 0.f, 0.f, 0.f};
  int kt0 = max(0, q0 - (WIN_ - 1)) >> 6;
  for (int kt = kt0; kt <= qt; ++kt) {
    int kb = kt * 64;
    {
      int r0 = w * 16 + (l >> 3), r1 = r0 + 8;
      int uu = l & 7;
      short8 k0v = *(const short8*)(kh + ((size_t)h * S_ + kb + r0) * HD_ + uu * 8);
      short8 k1v = *(const short8*)(kh + ((size_t)h * S_ + kb + r1) * HD_ + uu * 8);
      short8 v0v = *(const short8*)(vht + ((size_t)h * HD_ + r0) * S_ + kb + uu * 8);
      short8 v1v = *(const short8*)(vht + ((size_t)h * HD_ + r1) * S_ + kb + uu * 8);
      *(short8*)(Ks + r0 * 128 + ((uu ^ (r0 & 7)) << 4)) = k0v;
      *(short8*)(Ks + r1 * 128 + ((uu ^ (r1 & 7)) << 4)) = k1v;
      *(short8*)(Vs + r0 * 128 + ((uu ^ (r0 & 7)) << 4)) = v0v;
      *(short8*)(Vs + r1 * 128 + ((uu ^ (r1 & 7)) << 4)) = v1v;
    }
    __syncthreads();
    f32x4 st[4];
#pragma unroll
    for (int kf = 0; kf < 4; ++kf) {
      int key = kf * 16 + lo;
      short8 a0 = *(const short8*)(Ks + key * 128 + ((g ^ (key & 7)) << 4));
      short8 a1 = *(const short8*)(Ks + key * 128 + (((4 + g) ^ (key & 7)) << 4));
      f32x4 z = (f32x4){0.f, 0.f, 0.f, 0.f};
      z = __builtin_amdgcn_mfma_f32_16x16x32_bf16(a0, bq0, z, 0, 0, 0);
      z = __builtin_amdgcn_mfma_f32_16x16x32_bf16(a1, bq1, z, 0, 0, 0);
      st[kf] = z;
    }
    float p[16];
    float tmax = -1e30f;
#pragma unroll
    for (int kf = 0; kf < 4; ++kf)
#pragma unroll
      for (int r = 0; r < 4; ++r) {
        int key = kb + kf * 16 + g * 4 + r;
        float s = st[kf][r] * 0.125f;
        bool okm = (key <= q) && (q - key < WIN_);
        s = okm ? s : -1e30f;
        p[kf * 4 + r] = s;
        tmax = fmaxf(tmax, s);
      }
    tmax = fmaxf(tmax, __shfl_xor(tmax, 16));
    tmax = fmaxf(tmax, __shfl_xor(tmax, 32));
    float m_new = fmaxf(m_run, tmax);
    float corr = __expf(m_run - m_new);
    float tsum = 0.f;
#pragma unroll
    for (int i = 0; i < 16; ++i) {
      float pe = (p[i] > -1e29f) ? __expf(p[i] - m_new) : 0.f;
      p[i] = pe;
      tsum += pe;
    }
    tsum += __shfl_xor(tsum, 16);
    tsum += __shfl_xor(tsum, 32);
    l_run = l_run * corr + tsum;
    m_run = m_new;
#pragma unroll
    for (int kf = 0; kf < 4; ++kf)
#pragma unroll
      for (int pr = 0; pr < 2; ++pr) {
        int keyloc = kf * 16 + g * 4 + pr * 2;
        unsigned pk = (unsigned)f2bf(p[kf * 4 + pr * 2]) |
                      ((unsigned)f2bf(p[kf * 4 + pr * 2 + 1]) << 16);
        *(unsigned*)(Pw + lo * 128 + (((keyloc >> 3) ^ (lo & 7)) << 4) +
                     (keyloc & 7) * 2) = pk;
      }
    float c0 = __shfl(corr, g * 4 + 0), c1 = __shfl(corr, g * 4 + 1);
    float c2 = __shfl(corr, g * 4 + 2), c3 = __shfl(corr, g * 4 + 3);
#pragma unroll
    for (int nf = 0; nf < 4; ++nf) {
      o[nf][0] *= c0; o[nf][1] *= c1; o[nf][2] *= c2; o[nf][3] *= c3;
    }
    short8 ap0 = *(const short8*)(Pw + lo * 128 + ((g ^ (lo & 7)) << 4));
    short8 ap1 = *(const short8*)(Pw + lo * 128 + (((4 + g) ^ (lo & 7)) << 4));
#pragma unroll
    for (int nf = 0; nf < 4; ++nf) {
      int d = nf * 16 + lo;
      short8 v0 = *(const short8*)(Vs + d * 128 + ((g ^ (d & 7)) << 4));
      short8 v1 = *(const short8*)(Vs + d * 128 + (((4 + g) ^ (d & 7)) << 4));
      o[nf] = __builtin_amdgcn_mfma_f32_16x16x32_bf16(ap0, v0, o[nf], 0, 0, 0);
      o[nf] = __builtin_amdgcn_mfma_f32_16x16x32_bf16(ap1, v1, o[nf], 0, 0, 0);
    }
    __syncthreads();
  }
  float linv = 1.f / l_run;
  float i0 = __shfl(linv, g * 4 + 0), i1 = __shfl(linv, g * 4 + 1);
  float i2 = __shfl(linv, g * 4 + 2), i3 = __shfl(linv, g * 4 + 3);
#pragma unroll
  for (int nf = 0; nf < 4; ++nf) {
    int d = nf * 16 + lo;
    attn[(size_t)(qw + g * 4 + 0) * HID_ + h * HD_ + d] = f2bf(o[nf][0] * i0);
    attn[(size_t)(qw + g * 4 + 1) * HID_ + h * HD_ + d] = f2bf(o[nf][1] * i1);
    attn[(size_t)(qw + g * 4 + 2) * HID_ + h * HD_ + d] = f2bf(o[nf][2] * i2);
    attn[(size_t)(qw + g * 4 + 3) * HID_ + h * HD_ + d] = f2bf(o[nf][3] * i3);
  }
}

// ------------------- combine (+ split-K partial reduction) ------------------
__global__ __launch_bounds__(256) void combine_k(float* __restrict__ out,
                                                 const float* __restrict__ part,
                                                 const int* __restrict__ slot_of,
                                                 const float* __restrict__ topg) {
  int row = blockIdx.x, tid = threadIdx.x;
  int d0 = tid * 4;
  const size_t PS = (size_t)2 * S_ * HID_;
  int p0 = slot_of[row * 2], p1 = slot_of[row * 2 + 1];
  float g0 = topg[row * 2], g1 = topg[row * 2 + 1];
  float4 cur = *(float4*)&out[(size_t)row * HID_ + d0];
  float4 a0 = *(const float4*)&part[(size_t)p0 * HID_ + d0];
  float4 a1 = *(const float4*)&part[PS + (size_t)p0 * HID_ + d0];
  float4 b0 = *(const float4*)&part[(size_t)p1 * HID_ + d0];
  float4 b1 = *(const float4*)&part[PS + (size_t)p1 * HID_ + d0];
  cur.x += g0 * (a0.x + a1.x) + g1 * (b0.x + b1.x);
  cur.y += g0 * (a0.y + a1.y) + g1 * (b0.y + b1.y);
  cur.z += g0 * (a0.z + a1.z) + g1 * (b0.z + b1.z);
  cur.w += g0 * (a0.w + a1.w) + g1 * (b0.w + b1.w);
  *(float4*)&out[(size_t)row * HID_ + d0] = cur;
}

// ------------------------------ host launcher -------------------------------
extern "C" void kernel_launch(void* const* d_in, const int* in_sizes, int n_in,
                              void* d_out, int out_size, void* d_ws,
                              size_t ws_size, hipStream_t stream) {
  const float* x = (const float*)d_in[0];
  const float* rot = (const float*)d_in[1];
  const float* r1w = (const float*)d_in[2];
  const float* wq = (const float*)d_in[3];
  const float* wk = (const float*)d_in[4];
  const float* wv = (const float*)d_in[5];
  const float* wo = (const float*)d_in[6];
  const float* r2w = (const float*)d_in[7];
  const float* gw = (const float*)d_in[8];
  const float* w1 = (const float*)d_in[9];
  const float* w2 = (const float*)d_in[10];
  const float* w3 = (const float*)d_in[11];
  float* out = (float*)d_out;

  char* ws = (char*)d_ws;
  size_t off = 0;
  auto alloc = [&](size_t bytes) {
    char* p = ws + off;
    off += (bytes + 255) & ~(size_t)255;
    return p;
  };
  const size_t MB4 = (size_t)S_ * HID_ * 2;  // 4 MiB
  u16* wqkvoT = (u16*)alloc((size_t)4 * HID_ * HID_ * 2);
  u16* wqT = wqkvoT;
  u16* wkT = wqkvoT + (size_t)HID_ * HID_;
  u16* wvT = wqkvoT + (size_t)2 * HID_ * HID_;
  u16* woT = wqkvoT + (size_t)3 * HID_ * HID_;
  u16* w13T = (u16*)alloc((size_t)2 * NE_ * DFF_ * HID_ * 2);
  u16* w1T = w13T;
  u16* w3T = w13T + (size_t)NE_ * DFF_ * HID_;
  u16* w2T = (u16*)alloc((size_t)NE_ * HID_ * DFF_ * 2);
  char* uni = alloc((size_t)2 * S_ * DFF_ * 2);
  u16* ybf = (u16*)(uni);
  u16* qh = (u16*)(uni + MB4);
  u16* kh = (u16*)(uni + 2 * MB4);
  u16* vh = (u16*)(uni + 3 * MB4);
  u16* vht = (u16*)(uni + 4 * MB4);
  u16* attnb = (u16*)(uni + 5 * MB4);
  u16* h3 = (u16*)uni;           // alive during ffn1+swiglu
  float* partials = (float*)uni; // alive during ffn2+combine (h3 dead)
  u16* y2bf = (u16*)alloc(MB4);
  u16* h1 = (u16*)alloc((size_t)2 * S_ * DFF_ * 2);
  float* cost = (float*)alloc((size_t)S_ * 32 * 4);
  float* sint = (float*)alloc((size_t)S_ * 32 * 4);
  float* logits = (float*)alloc((size_t)S_ * NE_ * 4);
  int* topi = (int*)alloc((size_t)S_ * 2 * 4);
  float* topg = (float*)alloc((size_t)S_ * 2 * 4);
  int* ints = (int*)alloc(256);  // counts[8], ebase[8]
  int* counts = ints;
  int* ebase = ints + 8;
  int* slot_token = (int*)alloc((size_t)2 * S_ * 4);
  int* slot_of = (int*)alloc((size_t)S_ * 2 * 4);
  (void)ws_size; (void)in_sizes; (void)n_in; (void)out_size;

  // mega1: rms1 (0..2047) + rope (2048..2303) + qkvo conv (2304..3327)
  mega1_k<<<dim3(S_ + 256 + 1024), 256, 0, stream>>>(
      x, r1w, ybf, rot, cost, sint, wq, wk, wv, wo, wqkvoT);

  // QKV: grid (8,16,51): z<3 gemm, z[3,35) w3-conv, z[35,51) w2-conv t[0,2048)
  gemm3_k<0, 5><<<dim3(8, 16, 51), 256, 0, stream>>>(
      ybf, wqT, wkT, wvT, HID_, nullptr, nullptr, cost, sint,
      /*xres=w3 src*/ w3, /*outf=w13T dst*/ (float*)w13T, qh, kh, vh,
      w2, w2T);
  convT_u16_k<<<dim3(1, 32, 16), 256, 0, stream>>>(vh, vht, S_, HD_, (size_t)S_ * HD_);

  // mega attn: 512 attn + 8192 w1-conv + 2048 w2-conv (t[2048,4096))
  attn_conv_k<<<dim3(512 + 8192 + 2048), 256, 0, stream>>>(
      qh, kh, vht, attnb, w1, w13T, w2, w2T);

  // proj: grid (8,16,49): z<1 gemm, z[1,33) w3-conv, z[33,49) w2 t[4096,6144)
  gemm3_k<1, 5><<<dim3(8, 16, 49), 256, 0, stream>>>(
      attnb, woT, nullptr, nullptr, HID_, nullptr, nullptr,
      /*cost=w3 src*/ w3, nullptr, x, out, nullptr, /*o1=w13T dst*/ w13T,
      nullptr, w2, w2T);

  rms2_gate_k<<<dim3(S_), 256, 0, stream>>>(out, r2w, gw, y2bf, logits);
  route_k<<<dim3(1), 1024, 0, stream>>>(logits, topi, topg, counts, ebase,
                                        slot_token, slot_of);

  // ffn1: 1024 gemm blocks + 1024 w2-conv blocks (t[6144,8192), 2/block)
  gemm5_k<<<dim3(1024 + 1024), 512, 0, stream>>>(
      y2bf, w1T, w3T, HID_, counts, ebase, slot_token, h1, h3, w2, w2T);
  swiglu_k<<<dim3(8192), 256, 0, stream>>>(h1, h3);
  // ffn2 split-K=2: grid (n=8, m=16, z=e*2+kc)
  gemm3_k<4, 4><<<dim3(8, 16, 16), 256, 0, stream>>>(
      h1, w2T, nullptr, nullptr, DFF_ / 2, counts, ebase, nullptr, nullptr,
      nullptr, partials, nullptr, nullptr, nullptr, nullptr, nullptr);
  combine_k<<<dim3(S_), 256, 0, stream>>>(out, partials, slot_of, topg);
}

// Round 18
// 374.349 us; speedup vs baseline: 1.0110x; 1.0110x over previous
//
#include <hip/hip_runtime.h>
#include <hip/hip_bf16.h>
#include <stdint.h>

// ---------------------------------------------------------------------------
// TransformerBlock: rms1 -> QKV(+RoPE) -> window-512 flash attn -> out-proj(+x)
//                   -> rms2(+gate logits) -> top2 route -> grouped SwiGLU MoE -> +x2
// Round 18: REVERT to r16 (best measured, 375.4us). r17's equal-split of the
// w2-conv tiles was directionally negative: marginal conv cost is LOWER in the
// ffn1 window (compute-bound, idle HBM) than in the BW-loaded QKV/attn/proj
// windows, so r16's all-w2-in-ffn1 placement is the constrained optimum
// (w1/w3 conv cannot ride in ffn1's window -- ffn1 reads them).
// ---------------------------------------------------------------------------

#define S_ 2048
#define HID_ 1024
#define NH_ 16
#define HD_ 64
#define WIN_ 512
#define DFF_ 4096
#define NE_ 8

typedef unsigned short u16;
typedef __attribute__((ext_vector_type(8))) short short8;
typedef __attribute__((ext_vector_type(4))) float f32x4;

__device__ __forceinline__ u16 f2bf(float f) {
  union { float f; unsigned u; } v; v.f = f;
  unsigned r = (v.u + 0x7FFFu + ((v.u >> 16) & 1u)) >> 16;
  return (u16)r;
}
__device__ __forceinline__ float bf2f(u16 b) {
  union { unsigned u; float f; } v; v.u = ((unsigned)b) << 16;
  return v.f;
}

// async global->LDS, 16B per lane. LDS dest wave-uniform base + lane*16.
__device__ __forceinline__ void gload16(const void* g, void* l) {
  __builtin_amdgcn_global_load_lds(
      (const __attribute__((address_space(1))) void*)g,
      (__attribute__((address_space(3))) void*)l, 16, 0, 0);
}

template <int N>
__device__ __forceinline__ void waitcnt_vm() {
  static_assert(N == 0 || N == 2 || N == 4 || N == 6 || N == 8 || N == 12 ||
                N == 16 || N == 24, "unsupported vmcnt");
  if constexpr (N == 0) asm volatile("s_waitcnt vmcnt(0)" ::: "memory");
  else if constexpr (N == 2) asm volatile("s_waitcnt vmcnt(2)" ::: "memory");
  else if constexpr (N == 4) asm volatile("s_waitcnt vmcnt(4)" ::: "memory");
  else if constexpr (N == 6) asm volatile("s_waitcnt vmcnt(6)" ::: "memory");
  else if constexpr (N == 8) asm volatile("s_waitcnt vmcnt(8)" ::: "memory");
  else if constexpr (N == 12) asm volatile("s_waitcnt vmcnt(12)" ::: "memory");
  else if constexpr (N == 16) asm volatile("s_waitcnt vmcnt(16)" ::: "memory");
  else if constexpr (N == 24) asm volatile("s_waitcnt vmcnt(24)" ::: "memory");
}

// ------------- 64x64 f32->bf16 transpose tile (r10 proven, 256 thr) ---------
// LDS: element (k,n) at byte k*264 + ((n>>2)^((k>>2)&15))*8 + (n&3)*2.
// Needs 64*264 = 16896 bytes of T.
__device__ __forceinline__ void conv64(const float* __restrict__ Wm,
                                       u16* __restrict__ WTm, int K, int N,
                                       int n0, int k0, char* T, int tid) {
  int m = tid & 15, rr = tid >> 4;
#pragma unroll
  for (int p = 0; p < 4; ++p) {
    int k = p * 16 + rr;
    float4 v = *(const float4*)&Wm[(size_t)(k0 + k) * N + n0 + m * 4];
    uint2 pk;
    pk.x = (unsigned)f2bf(v.x) | ((unsigned)f2bf(v.y) << 16);
    pk.y = (unsigned)f2bf(v.z) | ((unsigned)f2bf(v.w) << 16);
    *(uint2*)(T + k * 264 + ((m ^ ((k >> 2) & 15)) << 3)) = pk;
  }
  __syncthreads();
#pragma unroll
  for (int p = 0; p < 4; ++p) {
    int n = p * 16 + rr;
    int un = n >> 2, lo2 = (n & 3) * 2;
    ushort4 o;
#pragma unroll
    for (int j = 0; j < 4; ++j) {
      int k = m * 4 + j;
      ((u16*)&o)[j] =
          *(const u16*)(T + k * 264 + ((un ^ ((k >> 2) & 15)) << 3) + lo2);
    }
    *(ushort4*)&WTm[(size_t)(n0 + n) * K + k0 + m * 4] = o;
  }
}

// bf16 [K][N] -> bf16 [N][K] (for V: [s][d] -> [d][s] per head)
__global__ __launch_bounds__(256) void convT_u16_k(const u16* __restrict__ W,
                                                   u16* __restrict__ WT,
                                                   int K, int N, size_t matStride) {
  __shared__ u16 t[64][66];
  const u16* Wm = W + (size_t)blockIdx.z * matStride;
  u16* WTm = WT + (size_t)blockIdx.z * matStride;
  int n0 = blockIdx.x * 64, k0 = blockIdx.y * 64;
  int tid = threadIdx.x;
  int c2 = (tid & 31) * 2, rr = tid >> 5;
#pragma unroll
  for (int it = 0; it < 8; ++it) {
    int r = it * 8 + rr;
    unsigned vv = *(const unsigned*)&Wm[(size_t)(k0 + r) * N + n0 + c2];
    t[c2][r] = (u16)vv;
    t[c2 + 1][r] = (u16)(vv >> 16);
  }
  __syncthreads();
#pragma unroll
  for (int it = 0; it < 8; ++it) {
    int n = it * 8 + rr;
    unsigned pk = (unsigned)t[n][c2] | ((unsigned)t[n][c2 + 1] << 16);
    *(unsigned*)&WTm[(size_t)(n0 + n) * K + k0 + c2] = pk;
  }
}

// ------------- mega1: rms1 (0..2047) + rope (2048..2303) + qkvo conv --------
__global__ __launch_bounds__(256) void mega1_k(
    const float* __restrict__ x, const float* __restrict__ rw,
    u16* __restrict__ y, const float* __restrict__ rot,
    float* __restrict__ cost, float* __restrict__ sint,
    const float* __restrict__ wq, const float* __restrict__ wk,
    const float* __restrict__ wv, const float* __restrict__ wo,
    u16* __restrict__ qkvoT) {
  __shared__ alignas(16) char SM[16896];
  int b = blockIdx.x, tid = threadIdx.x;
  if (b >= S_ + 256) {
    int cb = b - (S_ + 256);
    int z = cb >> 8, rem = cb & 255;
    const float* Wm = (z == 0) ? wq : (z == 1) ? wk : (z == 2) ? wv : wo;
    u16* WTm = qkvoT + (size_t)z * HID_ * HID_;
    conv64(Wm, WTm, HID_, HID_, (rem & 15) * 64, (rem >> 4) * 64, SM, tid);
    return;
  }
  if (b >= S_) {
    int id = (b - S_) * 256 + tid;
    int s = id >> 5, j = id & 31;
    cost[id] = rot[(size_t)s * 4096 + (size_t)(2 * j) * 64 + 2 * j];
    sint[id] = rot[(size_t)s * 4096 + (size_t)(2 * j + 1) * 64 + 2 * j];
    return;
  }
  int row = b;
  float* red = (float*)SM;
  const float4 v = *(const float4*)&x[(size_t)row * HID_ + tid * 4];
  float ss = v.x * v.x + v.y * v.y + v.z * v.z + v.w * v.w;
#pragma unroll
  for (int o = 32; o; o >>= 1) ss += __shfl_xor(ss, o);
  if ((tid & 63) == 0) red[tid >> 6] = ss;
  __syncthreads();
  float rstd = rsqrtf((red[0] + red[1] + red[2] + red[3]) * (1.f / HID_) + 1e-6f);
  const float4 w4 = *(const float4*)&rw[tid * 4];
  ushort4 o4;
  o4.x = f2bf(v.x * rstd * w4.x);
  o4.y = f2bf(v.y * rstd * w4.y);
  o4.z = f2bf(v.z * rstd * w4.z);
  o4.w = f2bf(v.w * rstd * w4.w);
  *(ushort4*)&y[(size_t)row * HID_ + tid * 4] = o4;
}

// ------------------------- rmsnorm 2 + gate logits --------------------------
__global__ __launch_bounds__(256) void rms2_gate_k(const float* __restrict__ x2,
                                                   const float* __restrict__ rw,
                                                   const float* __restrict__ gw,
                                                   u16* __restrict__ y2,
                                                   float* __restrict__ logits) {
  int row = blockIdx.x, tid = threadIdx.x;
  int wv = tid >> 6, ln = tid & 63;
  const float4 v = *(const float4*)&x2[(size_t)row * HID_ + tid * 4];
  float ss = v.x * v.x + v.y * v.y + v.z * v.z + v.w * v.w;
#pragma unroll
  for (int o = 32; o; o >>= 1) ss += __shfl_xor(ss, o);
  __shared__ float red[4];
  __shared__ float lred[4][8];
  if (ln == 0) red[wv] = ss;
  __syncthreads();
  float rstd = rsqrtf((red[0] + red[1] + red[2] + red[3]) * (1.f / HID_) + 1e-6f);
  const float4 w4 = *(const float4*)&rw[tid * 4];
  float yv[4];
  yv[0] = v.x * rstd * w4.x; yv[1] = v.y * rstd * w4.y;
  yv[2] = v.z * rstd * w4.z; yv[3] = v.w * rstd * w4.w;
  ushort4 o4;
  o4.x = f2bf(yv[0]); o4.y = f2bf(yv[1]); o4.z = f2bf(yv[2]); o4.w = f2bf(yv[3]);
  *(ushort4*)&y2[(size_t)row * HID_ + tid * 4] = o4;
  float le[8] = {0, 0, 0, 0, 0, 0, 0, 0};
  int d0 = tid * 4;
#pragma unroll
  for (int j = 0; j < 4; ++j) {
    const float* grow = &gw[(size_t)(d0 + j) * NE_];
#pragma unroll
    for (int e = 0; e < 8; ++e) le[e] += yv[j] * grow[e];
  }
#pragma unroll
  for (int e = 0; e < 8; ++e) {
    float t = le[e];
#pragma unroll
    for (int o = 32; o; o >>= 1) t += __shfl_xor(t, o);
    le[e] = t;
  }
  if (ln == 0)
#pragma unroll
    for (int e = 0; e < 8; ++e) lred[wv][e] = le[e];
  __syncthreads();
  if (tid < 8)
    logits[(size_t)row * NE_ + tid] =
        lred[0][tid] + lred[1][tid] + lred[2][tid] + lred[3][tid];
}

// ---------------------- routing: top2 + prefix + scatter --------------------
__global__ __launch_bounds__(1024) void route_k(const float* __restrict__ logits,
                                                int* __restrict__ topi,
                                                float* __restrict__ topg,
                                                int* __restrict__ counts,
                                                int* __restrict__ ebase,
                                                int* __restrict__ slot_token,
                                                int* __restrict__ slot_of) {
  __shared__ int cnt[8], bas[8], rnk[8];
  int tid = threadIdx.x;
  if (tid < 8) { cnt[tid] = 0; rnk[tid] = 0; }
  __syncthreads();
  int e0[2], e1[2];
  float g0[2], g1[2];
#pragma unroll
  for (int s = 0; s < 2; ++s) {
    int t = tid * 2 + s;
    const float* lg = &logits[(size_t)t * NE_];
    float v0 = -1e30f; int i0 = 0;
#pragma unroll
    for (int e = 0; e < 8; ++e) {
      float x = lg[e];
      if (x > v0) { v0 = x; i0 = e; }
    }
    float v1 = -1e30f; int i1 = 0;
#pragma unroll
    for (int e = 0; e < 8; ++e) {
      if (e == i0) continue;
      float x = lg[e];
      if (x > v1) { v1 = x; i1 = e; }
    }
    float ex = __expf(v1 - v0);
    e0[s] = i0; e1[s] = i1;
    g0[s] = 1.f / (1.f + ex);
    g1[s] = ex / (1.f + ex);
    topi[t * 2] = i0; topi[t * 2 + 1] = i1;
    topg[t * 2] = g0[s]; topg[t * 2 + 1] = g1[s];
    atomicAdd(&cnt[i0], 1);
    atomicAdd(&cnt[i1], 1);
  }
  __syncthreads();
  if (tid == 0) {
    int s = 0;
    for (int e = 0; e < 8; ++e) { bas[e] = s; s += cnt[e]; }
  }
  __syncthreads();
#pragma unroll
  for (int s = 0; s < 2; ++s) {
    int t = tid * 2 + s;
    int p0 = bas[e0[s]] + atomicAdd(&rnk[e0[s]], 1);
    int p1 = bas[e1[s]] + atomicAdd(&rnk[e1[s]], 1);
    slot_token[p0] = t; slot_token[p1] = t;
    slot_of[t * 2] = p0; slot_of[t * 2 + 1] = p1;
  }
  if (tid < 8) { counts[tid] = cnt[tid]; ebase[tid] = bas[tid]; }
}

// ----------------- GEMM: 4-wave 128^2 BK=32, SLOTS-deep pipeline ------------
// MODE 0: qkv (+ w3-conv arm for z>=3: src=xres, dst=(u16*)outf, mats 8..11)
// MODE 1: out-proj(+x) (+ w3-conv arm for z>=1: src=cost, dst=o1, mats 12..15)
// MODE 4: ffn2 split-K f32-partial
template <int MODE, int SLOTS>
__global__ __launch_bounds__(256, (SLOTS <= 3 ? 3 : (SLOTS <= 5 ? 2 : 1)))
void gemm3_k(
    const u16* __restrict__ A, const u16* __restrict__ B0,
    const u16* __restrict__ B1, const u16* __restrict__ B2, int K,
    const int* __restrict__ ecnt, const int* __restrict__ ebase,
    const float* __restrict__ cost, const float* __restrict__ sint,
    const float* __restrict__ xres, float* __restrict__ outf,
    u16* __restrict__ o0, u16* __restrict__ o1, u16* __restrict__ o2) {
  constexpr int WVM = 4 * (SLOTS - 2);
  __shared__ alignas(16) char smem[SLOTS * 16384];

  if constexpr (MODE == 0) {
    if (blockIdx.z >= 3) {  // w3-conv arm: lower-half mats -> w13T slots 8..11
      int idx = (blockIdx.z - 3) * 128 + blockIdx.y * 8 + blockIdx.x;
      int mt = idx >> 10, rem = idx & 1023;
      conv64(xres + (size_t)mt * HID_ * DFF_,
             (u16*)outf + (size_t)(8 + mt) * HID_ * DFF_, HID_, DFF_,
             (rem & 63) * 64, (rem >> 6) * 64, smem, threadIdx.x);
      return;
    }
  }
  if constexpr (MODE == 1) {
    if (blockIdx.z >= 1) {  // w3-conv arm: upper-half mats -> w13T slots 12..15
      int idx = (blockIdx.z - 1) * 128 + blockIdx.y * 8 + blockIdx.x;
      int mt = idx >> 10, rem = idx & 1023;
      conv64(cost + (size_t)(4 + mt) * HID_ * DFF_,
             o1 + (size_t)(12 + mt) * HID_ * DFF_, HID_, DFF_,
             (rem & 63) * 64, (rem >> 6) * 64, smem, threadIdx.x);
      return;
    }
  }

  int n0 = blockIdx.x * 128, m0 = blockIdx.y * 128;
  int cnt = 0, base = 0, kc = 0;
  const u16* Bp;
  u16* outb = o0;
  float* pout = outf;
  int rope = 0;
  if constexpr (MODE == 0) {
    int z = blockIdx.z;
    Bp = (z == 0) ? B0 : (z == 1) ? B1 : B2;
    outb = (z == 0) ? o0 : (z == 1) ? o1 : o2;
    rope = (z < 2) ? 1 : 0;
  } else if constexpr (MODE == 1) {
    Bp = B0;
  } else if constexpr (MODE == 4) {
    int e = blockIdx.z >> 1;
    kc = blockIdx.z & 1;
    cnt = ecnt[e]; base = ebase[e];
    if (m0 >= cnt) return;
    Bp = B0 + (size_t)e * HID_ * DFF_;
    pout = outf + (size_t)kc * ((size_t)2 * S_ * HID_);
  } else {
    int e = blockIdx.z;
    cnt = ecnt[e]; base = ebase[e];
    if (m0 >= cnt) return;
    Bp = B0 + (size_t)e * HID_ * DFF_;
  }

  int tid = threadIdx.x, w = tid >> 6, l = tid & 63, lo = l & 15, g = l >> 4;
  int wm = w >> 1, wn = w & 1;
  int KT = K >> 5;
  size_t rb = (MODE == 4) ? (size_t)DFF_ * 2 : (size_t)K * 2;
  size_t kcoff = (MODE == 4) ? (size_t)kc * (size_t)(DFF_ / 2) * 2 : 0;

  int lrow = l >> 2, lu = l & 3;
  const char* pA[2];
  const char* pB[2];
  int ldOff[2];
#pragma unroll
  for (int j = 0; j < 2; ++j) {
    int rA = j * 64 + w * 16 + lrow;
    int swz = (lu ^ ((rA >> 1) & 3)) << 4;
    size_t arow;
    if constexpr (MODE == 3 || MODE == 4) {
      arow = (size_t)(base + min(m0 + rA, cnt - 1));
    } else {
      arow = (size_t)(m0 + rA);
    }
    pA[j] = (const char*)A + arow * rb + kcoff + swz;
    pB[j] = (const char*)Bp + (size_t)(n0 + rA) * rb + kcoff + swz;
    ldOff[j] = (j * 64 + w * 16) * 64;
  }

  auto stage = [&](int t) {
    char* s = smem + (t % SLOTS) * 16384;
    size_t kb = (size_t)t * 64;
    gload16(pA[0] + kb, s + ldOff[0]);
    gload16(pA[1] + kb, s + ldOff[1]);
    gload16(pB[0] + kb, s + 8192 + ldOff[0]);
    gload16(pB[1] + kb, s + 8192 + ldOff[1]);
  };

  f32x4 acc[4][4];
#pragma unroll
  for (int i = 0; i < 4; ++i)
#pragma unroll
    for (int j = 0; j < 4; ++j) acc[i][j] = (f32x4){0.f, 0.f, 0.f, 0.f};

#pragma unroll
  for (int s = 0; s < SLOTS - 1; ++s) stage(min(s, KT - 1));
  waitcnt_vm<WVM>();
  __builtin_amdgcn_s_barrier();

  for (int t = 0; t < KT; ++t) {
    char* s = smem + (t % SLOTS) * 16384;
    stage(min(t + SLOTS - 1, KT - 1));
    short8 afr[4], bfr[4];
#pragma unroll
    for (int mi = 0; mi < 4; ++mi) {
      int r = wm * 64 + mi * 16 + lo;
      afr[mi] = *(const short8*)(s + r * 64 + ((g ^ ((r >> 1) & 3)) << 4));
    }
#pragma unroll
    for (int ni = 0; ni < 4; ++ni) {
      int r = wn * 64 + ni * 16 + lo;
      bfr[ni] = *(const short8*)(s + 8192 + r * 64 + ((g ^ ((r >> 1) & 3)) << 4));
    }
    asm volatile("s_waitcnt lgkmcnt(0)" ::: "memory");
    __builtin_amdgcn_s_setprio(1);
#pragma unroll
    for (int mi = 0; mi < 4; ++mi)
#pragma unroll
      for (int ni = 0; ni < 4; ++ni)
        acc[mi][ni] = __builtin_amdgcn_mfma_f32_16x16x32_bf16(afr[mi], bfr[ni], acc[mi][ni], 0, 0, 0);
    __builtin_amdgcn_s_setprio(0);
    if (t + 1 < KT)
      waitcnt_vm<WVM>();
    else
      waitcnt_vm<0>();
    __builtin_amdgcn_s_barrier();
  }
  asm volatile("s_waitcnt vmcnt(0) lgkmcnt(0)" ::: "memory");

  // epilogue
#pragma unroll
  for (int mi = 0; mi < 4; ++mi) {
    int lr = wm * 64 + mi * 16 + g * 4;
#pragma unroll
    for (int ni = 0; ni < 4; ++ni) {
      int c = n0 + wn * 64 + ni * 16 + lo;
#pragma unroll
      for (int r = 0; r < 4; ++r) {
        float v = acc[mi][ni][r];
        if constexpr (MODE == 0) {
          int row = m0 + lr + r;
          float p = __shfl_xor(v, 1);
          if (rope) {
            int dd = c & 63;
            float co = cost[(size_t)row * 32 + (dd >> 1)];
            float si = sint[(size_t)row * 32 + (dd >> 1)];
            v = (dd & 1) ? (co * v - si * p) : (co * v + si * p);
          }
          outb[((size_t)(c >> 6) * S_ + row) * HD_ + (c & 63)] = f2bf(v);
        } else if constexpr (MODE == 1) {
          int row = m0 + lr + r;
          outf[(size_t)row * HID_ + c] = v + xres[(size_t)row * HID_ + c];
        } else if constexpr (MODE == 4) {
          int m = m0 + lr + r;
          if (m < cnt) pout[(size_t)(base + m) * HID_ + c] = v;
        } else {
          int m = m0 + lr + r;
          if (m < cnt) outb[(size_t)(base + m) * HID_ + c] = f2bf(v);
        }
      }
    }
  }
}

// ----------------- GEMM: 8-wave 256^2 BK=64 (ffn1), 2-phase -----------------
// Flattened grid: blocks [0,1024) = ffn1 (x=bid&15, y=(bid>>4)&3, z=bid>>6);
// blocks [1024, 1024+4096) = w2-conv arm (2 x 64x64 tiles per 512-thr block).
__global__ __launch_bounds__(512, 2) void gemm5_k(
    const u16* __restrict__ A, const u16* __restrict__ B0,
    const u16* __restrict__ B1, int K, const int* __restrict__ ecnt,
    const int* __restrict__ ebase, const int* __restrict__ slot_token,
    u16* __restrict__ o0, u16* __restrict__ o1,
    const float* __restrict__ w2f, u16* __restrict__ w2T) {
  constexpr int BM = 256;
  constexpr int MROW = 128;
  constexpr int MI = 8;
  constexpr int MH = 4;
  constexpr int ABYTES = BM * 128;
  __shared__ alignas(16) char smem[ABYTES * 4];  // 128 KB

  int bid = blockIdx.x;
  if (bid >= 1024) {  // w2-conv arm: two tiles per block, split LDS halves
    int t2 = bid - 1024;
    int tid = threadIdx.x;
    int half = tid >> 8;
    int t = t2 * 2 + half;
    int mt = t >> 10, rem = t & 1023;
    conv64(w2f + (size_t)mt * DFF_ * HID_, w2T + (size_t)mt * DFF_ * HID_,
           DFF_, HID_, (rem & 15) * 64, (rem >> 4) * 64,
           smem + half * 16896, tid & 255);
    return;
  }

  char* ldsA = smem;
  char* ldsB = smem + 2 * ABYTES;
  int bx = bid & 15, by = (bid >> 4) & 3, bz = bid >> 6;
  int n0 = bx * BM, m0 = by * BM;
  int e = bz >> 1, mat = bz & 1;
  int cnt = ecnt[e], base = ebase[e];
  if (m0 >= cnt) return;
  const u16* Bp = (mat ? B1 : B0) + (size_t)e * DFF_ * HID_;
  u16* outb = mat ? o1 : o0;

  int tid = threadIdx.x, w = tid >> 6, l = tid & 63, lo = l & 15, g = l >> 4;
  int wm = w >> 2, wn = w & 3;
  int KT = K >> 6;
  size_t rb = (size_t)K * 2;

  int lrow = l >> 3, lu = l & 7;
  const char* pA[4];
  const char* pB[4];
  int ldOff[4];
#pragma unroll
  for (int j = 0; j < 4; ++j) {
    int rA = j * 64 + w * 8 + lrow;
    int swz = (lu ^ (rA & 7)) << 4;
    size_t arow = (size_t)slot_token[base + min(m0 + rA, cnt - 1)];
    pA[j] = (const char*)A + arow * rb + swz;
    pB[j] = (const char*)Bp + (size_t)(n0 + rA) * rb + swz;
    ldOff[j] = (j * 64 + w * 8) * 128;
  }

  auto stA = [&](int t, int j) {
    gload16(pA[j] + (size_t)t * 128, ldsA + (t & 1) * ABYTES + ldOff[j]);
  };
  auto stB = [&](int t, int j) {
    gload16(pB[j] + (size_t)t * 128, ldsB + (t & 1) * ABYTES + ldOff[j]);
  };
  auto rdA = [&](int d, int mi, int kh) {
    int row = wm * MROW + mi * 16 + lo;
    return *(const short8*)(ldsA + d * ABYTES + row * 128 +
                            (((kh * 4 + g) ^ (row & 7)) << 4));
  };
  auto rdB = [&](int d, int ni, int kh) {
    int row = wn * 64 + ni * 16 + lo;
    return *(const short8*)(ldsB + d * ABYTES + row * 128 +
                            (((kh * 4 + g) ^ (row & 7)) << 4));
  };

  f32x4 acc[MI][4];
#pragma unroll
  for (int i = 0; i < MI; ++i)
#pragma unroll
    for (int j = 0; j < 4; ++j) acc[i][j] = (f32x4){0.f, 0.f, 0.f, 0.f};

  // prologue: tile 0 in consumption order [B0-3, A0, A2, A1, A3]
  stB(0, 0); stB(0, 1); stB(0, 2); stB(0, 3);
  stA(0, 0); stA(0, 2); stA(0, 1); stA(0, 3);
  waitcnt_vm<2>();
  __builtin_amdgcn_s_barrier();

  for (int t = 0; t < KT; ++t) {
    int d = t & 1;
    int tn = min(t + 1, KT - 1);
    short8 afr[MH][2], bfr[4][2];
    // phase 0: q0 (A-even rows), both kh
    stB(tn, 0); stB(tn, 1); stB(tn, 2); stB(tn, 3);
#pragma unroll
    for (int i = 0; i < MH; ++i) {
      afr[i][0] = rdA(d, i, 0);
      afr[i][1] = rdA(d, i, 1);
    }
#pragma unroll
    for (int n = 0; n < 4; ++n) {
      bfr[n][0] = rdB(d, n, 0);
      bfr[n][1] = rdB(d, n, 1);
    }
    asm volatile("s_waitcnt lgkmcnt(0)" ::: "memory");
    __builtin_amdgcn_s_setprio(1);
#pragma unroll
    for (int kh = 0; kh < 2; ++kh)
#pragma unroll
      for (int i = 0; i < MH; ++i)
#pragma unroll
        for (int n = 0; n < 4; ++n)
          acc[i][n] = __builtin_amdgcn_mfma_f32_16x16x32_bf16(
              afr[i][kh], bfr[n][kh], acc[i][n], 0, 0, 0);
    __builtin_amdgcn_s_setprio(0);
    waitcnt_vm<4>();
    __builtin_amdgcn_s_barrier();
    // phase 1: q1 (A-odd rows), both kh
    stA(tn, 0); stA(tn, 2); stA(tn, 1); stA(tn, 3);
#pragma unroll
    for (int i = 0; i < MH; ++i) {
      afr[i][0] = rdA(d, MH + i, 0);
      afr[i][1] = rdA(d, MH + i, 1);
    }
    asm volatile("s_waitcnt lgkmcnt(0)" ::: "memory");
    __builtin_amdgcn_s_setprio(1);
#pragma unroll
    for (int kh = 0; kh < 2; ++kh)
#pragma unroll
      for (int i = 0; i < MH; ++i)
#pragma unroll
        for (int n = 0; n < 4; ++n)
          acc[MH + i][n] = __builtin_amdgcn_mfma_f32_16x16x32_bf16(
              afr[i][kh], bfr[n][kh], acc[MH + i][n], 0, 0, 0);
    __builtin_amdgcn_s_setprio(0);
    waitcnt_vm<2>();
    __builtin_amdgcn_s_barrier();
  }
  asm volatile("s_waitcnt vmcnt(0) lgkmcnt(0)" ::: "memory");

#pragma unroll
  for (int mi = 0; mi < MI; ++mi) {
    int lr = wm * MROW + mi * 16 + g * 4;
#pragma unroll
    for (int ni = 0; ni < 4; ++ni) {
      int c = n0 + wn * 64 + ni * 16 + lo;
#pragma unroll
      for (int r = 0; r < 4; ++r) {
        int m = m0 + lr + r;
        if (m < cnt) outb[(size_t)(base + m) * DFF_ + c] = f2bf(acc[mi][ni][r]);
      }
    }
  }
}

// ----------------------------- swiglu fuse ----------------------------------
__global__ __launch_bounds__(256) void swiglu_k(u16* __restrict__ h1,
                                                const u16* __restrict__ h3) {
  size_t i = ((size_t)blockIdx.x * 256 + threadIdx.x) * 8;
  short8 a = *(const short8*)(h1 + i);
  short8 b = *(const short8*)(h3 + i);
  short8 o;
#pragma unroll
  for (int j = 0; j < 8; ++j) {
    float x = bf2f((u16)a[j]), y = bf2f((u16)b[j]);
    float s = x / (1.f + __expf(-x));
    o[j] = (short)f2bf(s * y);
  }
  *(short8*)(h1 + i) = o;
}

// ------------- mega attn: attn (blocks 0..511) + w1-conv (8192) -------------
__global__ __launch_bounds__(256) void attn_conv_k(
    const u16* __restrict__ qh, const u16* __restrict__ kh,
    const u16* __restrict__ vht, u16* __restrict__ attn,
    const float* __restrict__ w1, u16* __restrict__ w13T) {
  __shared__ alignas(16) char SM[24576];
  int bx = blockIdx.x, tid = threadIdx.x;
  if (bx >= 512) {
    // w1: K=1024, N=4096; 1024 tiles (64n x 16k) per z; z in [0,8)
    int cb = bx - 512;
    int z = cb >> 10, rem = cb & 1023;
    const float* Wm = w1 + (size_t)z * HID_ * DFF_;
    u16* WTm = w13T + (size_t)z * HID_ * DFF_;
    conv64(Wm, WTm, HID_, DFF_, (rem & 63) * 64, (rem >> 6) * 64, SM, tid);
    return;
  }
  // ----- attention arm -----
  int qt = bx & 31, h = bx >> 5;
  char* Ks = SM;
  char* Vs = SM + 8192;
  char* Ps = SM + 16384;
  int w = tid >> 6, l = tid & 63, lo = l & 15, g = l >> 4;
  char* Pw = Ps + w * 2048;
  int q0 = qt * 64, qw = q0 + w * 16;
  const u16* qhh = qh + ((size_t)h * S_ + qw) * HD_;
  short8 bq0 = *(const short8*)(qhh + lo * 64 + g * 8);
  short8 bq1 = *(const short8*)(qhh + lo * 64 + 32 + g * 8);
  int q = qw + lo;
  float m_run = -1e30f, l_run = 0.f;
  f32x4 o[4];
#pragma unroll
  for (int i = 0; i < 4; ++i) o[i] = (f32x4){0.f, 0.f, 0.f, 0.f};
  int kt0 = max(0, q0 - (WIN_ - 1)) >> 6;
  for (int kt = kt0; kt <= qt; ++kt) {
    int kb = kt * 64;
    {
      int r0 = w * 16 + (l >> 3), r1 = r0 + 8;
      int uu = l & 7;
      short8 k0v = *(const short8*)(kh + ((size_t)h * S_ + kb + r0) * HD_ + uu * 8);
      short8 k1v = *(const short8*)(kh + ((size_t)h * S_ + kb + r1) * HD_ + uu * 8);
      short8 v0v = *(const short8*)(vht + ((size_t)h * HD_ + r0) * S_ + kb + uu * 8);
      short8 v1v = *(const short8*)(vht + ((size_t)h * HD_ + r1) * S_ + kb + uu * 8);
      *(short8*)(Ks + r0 * 128 + ((uu ^ (r0 & 7)) << 4)) = k0v;
      *(short8*)(Ks + r1 * 128 + ((uu ^ (r1 & 7)) << 4)) = k1v;
      *(short8*)(Vs + r0 * 128 + ((uu ^ (r0 & 7)) << 4)) = v0v;
      *(short8*)(Vs + r1 * 128 + ((uu ^ (r1 & 7)) << 4)) = v1v;
    }
    __syncthreads();
    f32x4 st[4];
#pragma unroll
    for (int kf = 0; kf < 4; ++kf) {
      int key = kf * 16 + lo;
      short8 a0 = *(const short8*)(Ks + key * 128 + ((g ^ (key & 7)) << 4));
      short8 a1 = *(const short8*)(Ks + key * 128 + (((4 + g) ^ (key & 7)) << 4));
      f32x4 z = (f32x4){0.f, 0.f, 0.f, 0.f};
      z = __builtin_amdgcn_mfma_f32_16x16x32_bf16(a0, bq0, z, 0, 0, 0);
      z = __builtin_amdgcn_mfma_f32_16x16x32_bf16(a1, bq1, z, 0, 0, 0);
      st[kf] = z;
    }
    float p[16];
    float tmax = -1e30f;
#pragma unroll
    for (int kf = 0; kf < 4; ++kf)
#pragma unroll
      for (int r = 0; r < 4; ++r) {
        int key = kb + kf * 16 + g * 4 + r;
        float s = st[kf][r] * 0.125f;
        bool okm = (key <= q) && (q - key < WIN_);
        s = okm ? s : -1e30f;
        p[kf * 4 + r] = s;
        tmax = fmaxf(tmax, s);
      }
    tmax = fmaxf(tmax, __shfl_xor(tmax, 16));
    tmax = fmaxf(tmax, __shfl_xor(tmax, 32));
    float m_new = fmaxf(m_run, tmax);
    float corr = __expf(m_run - m_new);
    float tsum = 0.f;
#pragma unroll
    for (int i = 0; i < 16; ++i) {
      float pe = (p[i] > -1e29f) ? __expf(p[i] - m_new) : 0.f;
      p[i] = pe;
      tsum += pe;
    }
    tsum += __shfl_xor(tsum, 16);
    tsum += __shfl_xor(tsum, 32);
    l_run = l_run * corr + tsum;
    m_run = m_new;
#pragma unroll
    for (int kf = 0; kf < 4; ++kf)
#pragma unroll
      for (int pr = 0; pr < 2; ++pr) {
        int keyloc = kf * 16 + g * 4 + pr * 2;
        unsigned pk = (unsigned)f2bf(p[kf * 4 + pr * 2]) |
                      ((unsigned)f2bf(p[kf * 4 + pr * 2 + 1]) << 16);
        *(unsigned*)(Pw + lo * 128 + (((keyloc >> 3) ^ (lo & 7)) << 4) +
                     (keyloc & 7) * 2) = pk;
      }
    float c0 = __shfl(corr, g * 4 + 0), c1 = __shfl(corr, g * 4 + 1);
    float c2 = __shfl(corr, g * 4 + 2), c3 = __shfl(corr, g * 4 + 3);
#pragma unroll
    for (int nf = 0; nf < 4; ++nf) {
      o[nf][0] *= c0; o[nf][1] *= c1; o[nf][2] *= c2; o[nf][3] *= c3;
    }
    short8 ap0 = *(const short8*)(Pw + lo * 128 + ((g ^ (lo & 7)) << 4));
    short8 ap1 = *(const short8*)(Pw + lo * 128 + (((4 + g) ^ (lo & 7)) << 4));
#pragma unroll
    for (int nf = 0; nf < 4; ++nf) {
      int d = nf * 16 + lo;
      short8 v0 = *(const short8*)(Vs + d * 128 + ((g ^ (d & 7)) << 4));
      short8 v1 = *(const short8*)(Vs + d * 128 + (((4 + g) ^ (d & 7)) << 4));
      o[nf] = __builtin_amdgcn_mfma_f32_16x16x32_bf16(ap0, v0, o[nf], 0, 0, 0);
      o[nf] = __builtin_amdgcn_mfma_f32_16x16x32_bf16(ap1, v1, o[nf], 0, 0, 0);
    }
    __syncthreads();
  }
  float linv = 1.f / l_run;
  float i0 = __shfl(linv, g * 4 + 0), i1 = __shfl(linv, g * 4 + 1);
  float i2 = __shfl(linv, g * 4 + 2), i3 = __shfl(linv, g * 4 + 3);
#pragma unroll
  for (int nf = 0; nf < 4; ++nf) {
    int d = nf * 16 + lo;
    attn[(size_t)(qw + g * 4 + 0) * HID_ + h * HD_ + d] = f2bf(o[nf][0] * i0);
    attn[(size_t)(qw + g * 4 + 1) * HID_ + h * HD_ + d] = f2bf(o[nf][1] * i1);
    attn[(size_t)(qw + g * 4 + 2) * HID_ + h * HD_ + d] = f2bf(o[nf][2] * i2);
    attn[(size_t)(qw + g * 4 + 3) * HID_ + h * HD_ + d] = f2bf(o[nf][3] * i3);
  }
}

// ------------------- combine (+ split-K partial reduction) ------------------
__global__ __launch_bounds__(256) void combine_k(float* __restrict__ out,
                                                 const float* __restrict__ part,
                                                 const int* __restrict__ slot_of,
                                                 const float* __restrict__ topg) {
  int row = blockIdx.x, tid = threadIdx.x;
  int d0 = tid * 4;
  const size_t PS = (size_t)2 * S_ * HID_;
  int p0 = slot_of[row * 2], p1 = slot_of[row * 2 + 1];
  float g0 = topg[row * 2], g1 = topg[row * 2 + 1];
  float4 cur = *(float4*)&out[(size_t)row * HID_ + d0];
  float4 a0 = *(const float4*)&part[(size_t)p0 * HID_ + d0];
  float4 a1 = *(const float4*)&part[PS + (size_t)p0 * HID_ + d0];
  float4 b0 = *(const float4*)&part[(size_t)p1 * HID_ + d0];
  float4 b1 = *(const float4*)&part[PS + (size_t)p1 * HID_ + d0];
  cur.x += g0 * (a0.x + a1.x) + g1 * (b0.x + b1.x);
  cur.y += g0 * (a0.y + a1.y) + g1 * (b0.y + b1.y);
  cur.z += g0 * (a0.z + a1.z) + g1 * (b0.z + b1.z);
  cur.w += g0 * (a0.w + a1.w) + g1 * (b0.w + b1.w);
  *(float4*)&out[(size_t)row * HID_ + d0] = cur;
}

// ------------------------------ host launcher -------------------------------
extern "C" void kernel_launch(void* const* d_in, const int* in_sizes, int n_in,
                              void* d_out, int out_size, void* d_ws,
                              size_t ws_size, hipStream_t stream) {
  const float* x = (const float*)d_in[0];
  const float* rot = (const float*)d_in[1];
  const float* r1w = (const float*)d_in[2];
  const float* wq = (const float*)d_in[3];
  const float* wk = (const float*)d_in[4];
  const float* wv = (const float*)d_in[5];
  const float* wo = (const float*)d_in[6];
  const float* r2w = (const float*)d_in[7];
  const float* gw = (const float*)d_in[8];
  const float* w1 = (const float*)d_in[9];
  const float* w2 = (const float*)d_in[10];
  const float* w3 = (const float*)d_in[11];
  float* out = (float*)d_out;

  char* ws = (char*)d_ws;
  size_t off = 0;
  auto alloc = [&](size_t bytes) {
    char* p = ws + off;
    off += (bytes + 255) & ~(size_t)255;
    return p;
  };
  const size_t MB4 = (size_t)S_ * HID_ * 2;  // 4 MiB
  u16* wqkvoT = (u16*)alloc((size_t)4 * HID_ * HID_ * 2);
  u16* wqT = wqkvoT;
  u16* wkT = wqkvoT + (size_t)HID_ * HID_;
  u16* wvT = wqkvoT + (size_t)2 * HID_ * HID_;
  u16* woT = wqkvoT + (size_t)3 * HID_ * HID_;
  u16* w13T = (u16*)alloc((size_t)2 * NE_ * DFF_ * HID_ * 2);
  u16* w1T = w13T;
  u16* w3T = w13T + (size_t)NE_ * DFF_ * HID_;
  u16* w2T = (u16*)alloc((size_t)NE_ * HID_ * DFF_ * 2);
  char* uni = alloc((size_t)2 * S_ * DFF_ * 2);
  u16* ybf = (u16*)(uni);
  u16* qh = (u16*)(uni + MB4);
  u16* kh = (u16*)(uni + 2 * MB4);
  u16* vh = (u16*)(uni + 3 * MB4);
  u16* vht = (u16*)(uni + 4 * MB4);
  u16* attnb = (u16*)(uni + 5 * MB4);
  u16* h3 = (u16*)uni;           // alive during ffn1+swiglu
  float* partials = (float*)uni; // alive during ffn2+combine (h3 dead)
  u16* y2bf = (u16*)alloc(MB4);
  u16* h1 = (u16*)alloc((size_t)2 * S_ * DFF_ * 2);
  float* cost = (float*)alloc((size_t)S_ * 32 * 4);
  float* sint = (float*)alloc((size_t)S_ * 32 * 4);
  float* logits = (float*)alloc((size_t)S_ * NE_ * 4);
  int* topi = (int*)alloc((size_t)S_ * 2 * 4);
  float* topg = (float*)alloc((size_t)S_ * 2 * 4);
  int* ints = (int*)alloc(256);  // counts[8], ebase[8]
  int* counts = ints;
  int* ebase = ints + 8;
  int* slot_token = (int*)alloc((size_t)2 * S_ * 4);
  int* slot_of = (int*)alloc((size_t)S_ * 2 * 4);
  (void)ws_size; (void)in_sizes; (void)n_in; (void)out_size;

  // mega1: rms1 (0..2047) + rope (2048..2303) + qkvo conv (2304..3327)
  mega1_k<<<dim3(S_ + 256 + 1024), 256, 0, stream>>>(
      x, r1w, ybf, rot, cost, sint, wq, wk, wv, wo, wqkvoT);

  // QKV: grid (8,16,35): z<3 gemm, z>=3 w3-conv (mats 0..3 -> slots 8..11)
  gemm3_k<0, 5><<<dim3(8, 16, 35), 256, 0, stream>>>(
      ybf, wqT, wkT, wvT, HID_, nullptr, nullptr, cost, sint,
      /*xres=w3 src*/ w3, /*outf=w13T dst*/ (float*)w13T, qh, kh, vh);
  convT_u16_k<<<dim3(1, 32, 16), 256, 0, stream>>>(vh, vht, S_, HD_, (size_t)S_ * HD_);

  // mega attn: 512 attn blocks + 8192 w1-conv blocks
  attn_conv_k<<<dim3(512 + 8192), 256, 0, stream>>>(
      qh, kh, vht, attnb, w1, w13T);

  // proj: grid (8,16,33): z<1 gemm, z>=1 w3-conv (mats 4..7 -> slots 12..15)
  gemm3_k<1, 5><<<dim3(8, 16, 33), 256, 0, stream>>>(
      attnb, woT, nullptr, nullptr, HID_, nullptr, nullptr,
      /*cost=w3 src*/ w3, nullptr, x, out, nullptr, /*o1=w13T dst*/ w13T,
      nullptr);

  rms2_gate_k<<<dim3(S_), 256, 0, stream>>>(out, r2w, gw, y2bf, logits);
  route_k<<<dim3(1), 1024, 0, stream>>>(logits, topi, topg, counts, ebase,
                                        slot_token, slot_of);

  // ffn1: flattened grid 1024 gemm blocks + 4096 w2-conv blocks
  gemm5_k<<<dim3(1024 + 4096), 512, 0, stream>>>(
      y2bf, w1T, w3T, HID_, counts, ebase, slot_token, h1, h3, w2, w2T);
  swiglu_k<<<dim3(8192), 256, 0, stream>>>(h1, h3);
  // ffn2 split-K=2: grid (n=8, m=16, z=e*2+kc)
  gemm3_k<4, 4><<<dim3(8, 16, 16), 256, 0, stream>>>(
      h1, w2T, nullptr, nullptr, DFF_ / 2, counts, ebase, nullptr, nullptr,
      nullptr, partials, nullptr, nullptr, nullptr);
  combine_k<<<dim3(S_), 256, 0, stream>>>(out, partials, slot_of, topg);
}